// Round 3
// baseline (1353.829 us; speedup 1.0000x reference)
//
#include <hip/hip_runtime.h>

using bf16x8 = __attribute__((ext_vector_type(8))) short;
using short8 = __attribute__((ext_vector_type(8))) short;
using f32x4  = __attribute__((ext_vector_type(4))) float;
using u32x4  = __attribute__((ext_vector_type(4))) unsigned;

#define T_SEQ 512
#define MFMA(A, B, C) __builtin_amdgcn_mfma_f32_16x16x32_bf16((A), (B), (C), 0, 0, 0)

// Truncation split: hi = bf16-truncate(v) (exact high 16 bits), residual computed
// exactly in f32 (same-exponent subtract), lo = bf16-truncate(residual).
// Effective 16-bit-mantissa representation; error ~2^-16 rel.
__device__ __forceinline__ void split8_tr(f32x4 a, f32x4 b, bf16x8& hi, bf16x8& lo) {
    u32x4 ua = __builtin_bit_cast(u32x4, a);
    u32x4 ub = __builtin_bit_cast(u32x4, b);
    u32x4 m  = {0xffff0000u, 0xffff0000u, 0xffff0000u, 0xffff0000u};
    f32x4 ra = a - __builtin_bit_cast(f32x4, ua & m);   // exact residual
    f32x4 rb = b - __builtin_bit_cast(f32x4, ub & m);
    short8 sa  = __builtin_bit_cast(short8, a);
    short8 sb  = __builtin_bit_cast(short8, b);
    short8 sra = __builtin_bit_cast(short8, ra);
    short8 srb = __builtin_bit_cast(short8, rb);
    hi = __builtin_shufflevector(sa, sb, 1, 3, 5, 7, 9, 11, 13, 15);
    lo = __builtin_shufflevector(sra, srb, 1, 3, 5, 7, 9, 11, 13, 15);
}

__device__ __forceinline__ void pack_frag_tr(const float (&hf)[8], bf16x8& hi, bf16x8& lo) {
    f32x4 a = {hf[0], hf[1], hf[2], hf[3]};
    f32x4 b = {hf[4], hf[5], hf[6], hf[7]};
    split8_tr(a, b, hi, lo);
}

__device__ __forceinline__ float sigmf(float v) { return 1.f / (1.f + __expf(-v)); }
__device__ __forceinline__ float tanhf_(float v) {
    v = fminf(fmaxf(v, -15.f), 15.f);
    float e = __expf(-2.f * v);
    return (1.f - e) / (1.f + e);
}

// Gate math for 8 hidden units per lane. arz tiles 0..3 (r: 0,1  z: 2,3),
// axn/ahn: n-gate input-side / hidden-side (tiles 4,5). hf updated in place.
__device__ __forceinline__ void gru_gate8(const f32x4 (&arz)[4], const f32x4 (&axn)[2],
                                          const f32x4 (&ahn)[2], float (&hf)[8]) {
    #pragma unroll
    for (int s = 0; s < 2; ++s) {          // s=0: units 4q+j, s=1: units 16+4q+j
        #pragma unroll
        for (int j = 0; j < 4; ++j) {
            float r = sigmf(arz[s][j]);
            float z = sigmf(arz[2 + s][j]);
            float nn = tanhf_(axn[s][j] + r * ahn[s][j]);
            float& h = hf[4 * s + j];
            h = nn + z * (h - nn);
        }
    }
}

// One GRU layer step for 16 batches on one wave.
// inh/inl: input fragment (x_t or h0_prev). sth/stl: state fragment h[t-1].
// Off-chain work first (input-side products, bias as C-in), h-dependent last.
__device__ __forceinline__ void layer_step(
    const bf16x8 (&Wxh)[6], const bf16x8 (&Wxl)[6],
    const bf16x8 (&Whh)[6], const bf16x8 (&Whl)[6],
    const f32x4 (&brz)[4], const f32x4 (&bxn)[2], const f32x4 (&bhn)[2],
    bf16x8 inh, bf16x8 inl, bf16x8 sth, bf16x8 stl,
    float (&hf)[8], bf16x8& outh, bf16x8& outl)
{
    f32x4 arz[4], axn[2], ahn[2];
    #pragma unroll
    for (int tt = 0; tt < 4; ++tt) {
        f32x4 a = MFMA(Wxh[tt], inh, brz[tt]);
        a = MFMA(Wxh[tt], inl, a);
        a = MFMA(Wxl[tt], inh, a);
        a = MFMA(Whh[tt], sth, a);       // chain starts here
        a = MFMA(Whh[tt], stl, a);
        a = MFMA(Whl[tt], sth, a);
        arz[tt] = a;
    }
    #pragma unroll
    for (int tt = 0; tt < 2; ++tt) {
        f32x4 a = MFMA(Wxh[4 + tt], inh, bxn[tt]);
        a = MFMA(Wxh[4 + tt], inl, a);
        a = MFMA(Wxl[4 + tt], inh, a);
        axn[tt] = a;
        f32x4 b = MFMA(Whh[4 + tt], sth, bhn[tt]);
        b = MFMA(Whh[4 + tt], stl, b);
        b = MFMA(Whl[4 + tt], sth, b);
        ahn[tt] = b;
    }
    gru_gate8(arz, axn, ahn, hf);
    pack_frag_tr(hf, outh, outl);
}

// One wave = 16 batches. D = W(96x32)*h(32x16b). Per-lane: batch = b0+(lane&15),
// q = lane>>4; frag elements 0..3 = units 4q+j, 4..7 = units 16+4q+j (same map
// for A and B frags -> correct under any k-slot convention). D: col=lane&15,
// row=4q+reg (m89-verified).
__global__ __launch_bounds__(64, 1)
void gru2_mfma(const float* __restrict__ x,
               const float* __restrict__ W_ih0, const float* __restrict__ W_hh0,
               const float* __restrict__ b_ih0, const float* __restrict__ b_hh0,
               const float* __restrict__ W_ih1, const float* __restrict__ W_hh1,
               const float* __restrict__ b_ih1, const float* __restrict__ b_hh1,
               const float* __restrict__ W_proj, const float* __restrict__ b_proj,
               float* __restrict__ out)
{
    const int lane = threadIdx.x;
    const int r16  = lane & 15;
    const int q    = lane >> 4;
    const int b0   = blockIdx.x * 16;

    // ---- weight fragments (hi/lo truncation split), register-resident ----
    bf16x8 Wh[4][6], Wl[4][6];
    {
        const float* Ws[4] = {W_ih0, W_hh0, W_ih1, W_hh1};
        #pragma unroll
        for (int m = 0; m < 4; ++m) {
            #pragma unroll
            for (int t = 0; t < 6; ++t) {
                const float* p = Ws[m] + (16 * t + r16) * 32 + 4 * q;
                split8_tr(*(const f32x4*)p, *(const f32x4*)(p + 16), Wh[m][t], Wl[m][t]);
            }
        }
    }

    // ---- bias fragments (acc layout: element reg -> row 16t+4q+reg) ----
    f32x4 brz0[4], brz1[4], bxn0[2], bhn0[2], bxn1[2], bhn1[2];
    #pragma unroll
    for (int t = 0; t < 4; ++t) {
        brz0[t] = *(const f32x4*)(b_ih0 + 16 * t + 4 * q) + *(const f32x4*)(b_hh0 + 16 * t + 4 * q);
        brz1[t] = *(const f32x4*)(b_ih1 + 16 * t + 4 * q) + *(const f32x4*)(b_hh1 + 16 * t + 4 * q);
    }
    #pragma unroll
    for (int t = 0; t < 2; ++t) {
        bxn0[t] = *(const f32x4*)(b_ih0 + 64 + 16 * t + 4 * q);
        bhn0[t] = *(const f32x4*)(b_hh0 + 64 + 16 * t + 4 * q);
        bxn1[t] = *(const f32x4*)(b_ih1 + 64 + 16 * t + 4 * q);
        bhn1[t] = *(const f32x4*)(b_hh1 + 64 + 16 * t + 4 * q);
    }

    // ---- state ----
    bf16x8 h0h = {}, h0l = {}, h1h = {}, h1l = {};
    float h0f[8] = {}, h1f[8] = {};

    const float* xp = x + (size_t)(b0 + r16) * (T_SEQ * 32) + 4 * q;
    f32x4 xA = *(const f32x4*)(xp);
    f32x4 xB = *(const f32x4*)(xp + 16);

    // ---- prologue: L0 step t=0 (h0[-1] = 0) ----
    {
        bf16x8 xh, xl;
        split8_tr(xA, xB, xh, xl);
        xA = *(const f32x4*)(xp + 32);       // prefetch x[1]
        xB = *(const f32x4*)(xp + 32 + 16);
        bf16x8 zz = {};
        layer_step(Wh[0], Wl[0], Wh[1], Wl[1], brz0, bxn0, bhn0,
                   xh, xl, zz, zz, h0f, h0h, h0l);
    }

    // ---- main loop: L0 computes h0[t] while L1 computes h1[t-1] ----
    #pragma unroll 1
    for (int t = 1; t < T_SEQ; ++t) {
        bf16x8 xh, xl;
        split8_tr(xA, xB, xh, xl);           // x[t] (loaded last iteration)
        int tn = (t < T_SEQ - 1) ? t + 1 : t;
        xA = *(const f32x4*)(xp + tn * 32);  // prefetch x[t+1]
        xB = *(const f32x4*)(xp + tn * 32 + 16);

        // L1 for time t-1: input = h0[t-1] (current h0 frags), state h1[t-2]
        layer_step(Wh[2], Wl[2], Wh[3], Wl[3], brz1, bxn1, bhn1,
                   h0h, h0l, h1h, h1l, h1f, h1h, h1l);
        // L0 for time t: input = x[t], state h0[t-1] -> overwrites h0 frags
        layer_step(Wh[0], Wl[0], Wh[1], Wl[1], brz0, bxn0, bhn0,
                   xh, xl, h0h, h0l, h0f, h0h, h0l);
    }

    // ---- epilogue: L1 for final step (input = h0[511], state h1[510]) ----
    layer_step(Wh[2], Wl[2], Wh[3], Wl[3], brz1, bxn1, bhn1,
               h0h, h0l, h1h, h1l, h1f, h1h, h1l);

    // ---- projection: out[b][o] = b_proj[o] + sum_u W_proj[o][u] * h1[u] ----
    const float* pp = W_proj + r16 * 32 + 4 * q;
    bf16x8 Wph, Wpl;
    split8_tr(*(const f32x4*)pp, *(const f32x4*)(pp + 16), Wph, Wpl);
    f32x4 accp = *(const f32x4*)(b_proj + 4 * q);   // element reg -> output 4q+reg
    accp = MFMA(Wph, h1h, accp);
    accp = MFMA(Wph, h1l, accp);
    accp = MFMA(Wpl, h1h, accp);

    #pragma unroll
    for (int rg = 0; rg < 4; ++rg)
        out[(b0 + r16) * 16 + 4 * q + rg] = accp[rg];
}

extern "C" void kernel_launch(void* const* d_in, const int* in_sizes, int n_in,
                              void* d_out, int out_size, void* d_ws, size_t ws_size,
                              hipStream_t stream) {
    const float* x      = (const float*)d_in[0];
    const float* W_ih0  = (const float*)d_in[1];
    const float* W_hh0  = (const float*)d_in[2];
    const float* b_ih0  = (const float*)d_in[3];
    const float* b_hh0  = (const float*)d_in[4];
    const float* W_ih1  = (const float*)d_in[5];
    const float* W_hh1  = (const float*)d_in[6];
    const float* b_ih1  = (const float*)d_in[7];
    const float* b_hh1  = (const float*)d_in[8];
    const float* W_proj = (const float*)d_in[9];
    const float* b_proj = (const float*)d_in[10];
    float* out = (float*)d_out;

    const int nb   = in_sizes[0] / (T_SEQ * 32);   // 4096 batch elements
    const int grid = nb / 16;                      // 16 batches per 1-wave block

    hipLaunchKernelGGL(gru2_mfma, dim3(grid), dim3(64), 0, stream,
                       x, W_ih0, W_hh0, b_ih0, b_hh0,
                       W_ih1, W_hh1, b_ih1, b_hh1, W_proj, b_proj, out);
}

// Round 4
// 871.942 us; speedup vs baseline: 1.5527x; 1.5527x over previous
//
#include <hip/hip_runtime.h>

using bf16x8 = __attribute__((ext_vector_type(8))) short;
using short8 = __attribute__((ext_vector_type(8))) short;
using f32x4  = __attribute__((ext_vector_type(4))) float;
using u32x4  = __attribute__((ext_vector_type(4))) unsigned;

#define T_SEQ 512
#define MFMA(A, B, C) __builtin_amdgcn_mfma_f32_16x16x32_bf16((A), (B), (C), 0, 0, 0)

// Truncation split: hi = bf16-truncate(v), lo = bf16-truncate(v - hi) (residual exact).
__device__ __forceinline__ void split8_tr(f32x4 a, f32x4 b, bf16x8& hi, bf16x8& lo) {
    u32x4 ua = __builtin_bit_cast(u32x4, a);
    u32x4 ub = __builtin_bit_cast(u32x4, b);
    u32x4 m  = {0xffff0000u, 0xffff0000u, 0xffff0000u, 0xffff0000u};
    f32x4 ra = a - __builtin_bit_cast(f32x4, ua & m);
    f32x4 rb = b - __builtin_bit_cast(f32x4, ub & m);
    short8 sa  = __builtin_bit_cast(short8, a);
    short8 sb  = __builtin_bit_cast(short8, b);
    short8 sra = __builtin_bit_cast(short8, ra);
    short8 srb = __builtin_bit_cast(short8, rb);
    hi = __builtin_shufflevector(sa, sb, 1, 3, 5, 7, 9, 11, 13, 15);
    lo = __builtin_shufflevector(sra, srb, 1, 3, 5, 7, 9, 11, 13, 15);
}

__device__ __forceinline__ void pack_frag_tr(const float (&hf)[8], bf16x8& hi, bf16x8& lo) {
    f32x4 a = {hf[0], hf[1], hf[2], hf[3]};
    f32x4 b = {hf[4], hf[5], hf[6], hf[7]};
    split8_tr(a, b, hi, lo);
}

// Fast gates: v_exp + v_rcp (no full-precision division sequences).
__device__ __forceinline__ float sigmf(float v) {
    return __builtin_amdgcn_rcpf(1.f + __expf(-v));
}
__device__ __forceinline__ float tanhf_(float v) {
    v = fminf(fmaxf(v, -15.f), 15.f);
    float e = __expf(-2.f * v);
    float r = __builtin_amdgcn_rcpf(1.f + e);
    return fmaf(-2.f * e, r, 1.f);      // 1 - 2e/(1+e)
}

// Gate math for one layer's 8 acc chains: a[0..3]=rz tiles, a[4..5]=xn, a[6..7]=hn.
__device__ __forceinline__ void gate8(const f32x4 (&a)[8], float (&hf)[8]) {
    #pragma unroll
    for (int s = 0; s < 2; ++s) {
        #pragma unroll
        for (int j = 0; j < 4; ++j) {
            float r = sigmf(a[s][j]);
            float z = sigmf(a[2 + s][j]);
            float nn = tanhf_(fmaf(r, a[6 + s][j], a[4 + s][j]));
            float& h = hf[4 * s + j];
            h = nn + z * (h - nn);
        }
    }
}

// One wave = 16 batches. D = W(96x32)*in(32x16b). Per-lane: batch = b0+(lane&15),
// q = lane>>4; frag elements 0..3 = units 4q+j, 4..7 = units 16+4q+j (same map for
// A and B frags -> correct under any k-slot convention). D: col=lane&15, row=4q+reg.
__global__ __launch_bounds__(64, 1)
void gru2_mfma(const float* __restrict__ x,
               const float* __restrict__ W_ih0, const float* __restrict__ W_hh0,
               const float* __restrict__ b_ih0, const float* __restrict__ b_hh0,
               const float* __restrict__ W_ih1, const float* __restrict__ W_hh1,
               const float* __restrict__ b_ih1, const float* __restrict__ b_hh1,
               const float* __restrict__ W_proj, const float* __restrict__ b_proj,
               float* __restrict__ out)
{
    const int lane = threadIdx.x;
    const int r16  = lane & 15;
    const int q    = lane >> 4;
    const int b0   = blockIdx.x * 16;

    // ---- weight fragments (hi/lo truncation split), register-resident ----
    // m: 0=W_ih0, 1=W_hh0, 2=W_ih1, 3=W_hh1; t: M-tile (rows 16t..16t+15)
    bf16x8 Wh[4][6], Wl[4][6];
    {
        const float* Ws[4] = {W_ih0, W_hh0, W_ih1, W_hh1};
        #pragma unroll
        for (int m = 0; m < 4; ++m) {
            #pragma unroll
            for (int t = 0; t < 6; ++t) {
                const float* p = Ws[m] + (16 * t + r16) * 32 + 4 * q;
                split8_tr(*(const f32x4*)p, *(const f32x4*)(p + 16), Wh[m][t], Wl[m][t]);
            }
        }
    }

    // ---- bias fragments (acc layout: element reg -> row 16t+4q+reg) ----
    f32x4 brz0[4], brz1[4], bxn0[2], bhn0[2], bxn1[2], bhn1[2];
    #pragma unroll
    for (int t = 0; t < 4; ++t) {
        brz0[t] = *(const f32x4*)(b_ih0 + 16 * t + 4 * q) + *(const f32x4*)(b_hh0 + 16 * t + 4 * q);
        brz1[t] = *(const f32x4*)(b_ih1 + 16 * t + 4 * q) + *(const f32x4*)(b_hh1 + 16 * t + 4 * q);
    }
    #pragma unroll
    for (int t = 0; t < 2; ++t) {
        bxn0[t] = *(const f32x4*)(b_ih0 + 64 + 16 * t + 4 * q);
        bhn0[t] = *(const f32x4*)(b_hh0 + 64 + 16 * t + 4 * q);
        bxn1[t] = *(const f32x4*)(b_ih1 + 64 + 16 * t + 4 * q);
        bhn1[t] = *(const f32x4*)(b_hh1 + 64 + 16 * t + 4 * q);
    }

    // ---- state ----
    bf16x8 H0h = {}, H0l = {}, H1h = {}, H1l = {};
    float h0f[8] = {}, h1f[8] = {};

    const float* xp = x + (size_t)(b0 + r16) * (T_SEQ * 32) + 4 * q;
    f32x4 xA = *(const f32x4*)(xp);
    f32x4 xB = *(const f32x4*)(xp + 16);

    // ---- prologue: L0 step t=0 (h0[-1] = 0 -> no h-side products; hn acc = bias) ----
    {
        bf16x8 xh, xl;
        split8_tr(xA, xB, xh, xl);
        xA = *(const f32x4*)(xp + 32);
        xB = *(const f32x4*)(xp + 48);
        f32x4 a[8];
        #pragma unroll
        for (int tt = 0; tt < 4; ++tt) {
            f32x4 c = MFMA(Wh[0][tt], xh, brz0[tt]);
            c = MFMA(Wh[0][tt], xl, c);
            a[tt] = MFMA(Wl[0][tt], xh, c);
        }
        #pragma unroll
        for (int s = 0; s < 2; ++s) {
            f32x4 c = MFMA(Wh[0][4 + s], xh, bxn0[s]);
            c = MFMA(Wh[0][4 + s], xl, c);
            a[4 + s] = MFMA(Wl[0][4 + s], xh, c);
            a[6 + s] = bhn0[s];
        }
        gate8(a, h0f);
        pack_frag_tr(h0f, H0h, H0l);
    }

    // ---- main loop: fused dual step. L1 computes h1[t-1], L0 computes h0[t].
    // All 72 MFMAs are issuable at step start; emitted round-robin across 16
    // independent accumulator chains so consecutive dependent MFMAs are >=8
    // issues apart (latency hidden without TLP).
    #pragma unroll 1
    for (int t = 1; t < T_SEQ; ++t) {
        bf16x8 xh, xl;
        split8_tr(xA, xB, xh, xl);               // x[t]
        const float* nx = xp + (size_t)((t + 1 < T_SEQ) ? t + 1 : t) * 32;
        f32x4 nA = *(const f32x4*)(nx);          // prefetch x[t+1]
        f32x4 nB = *(const f32x4*)(nx + 16);

        f32x4 acc[16];
        // chains: 0-3 L0 rz | 4-5 L0 xn | 6-7 L0 hn | 8-11 L1 rz | 12-13 L1 xn | 14-15 L1 hn
        // round 0: hi-W x hi-in (C = bias)
        #pragma unroll
        for (int tt = 0; tt < 4; ++tt) {
            acc[tt]     = MFMA(Wh[0][tt], xh,  brz0[tt]);
            acc[8 + tt] = MFMA(Wh[2][tt], H0h, brz1[tt]);
        }
        #pragma unroll
        for (int s = 0; s < 2; ++s) {
            acc[4 + s]  = MFMA(Wh[0][4 + s], xh,  bxn0[s]);
            acc[6 + s]  = MFMA(Wh[1][4 + s], H0h, bhn0[s]);
            acc[12 + s] = MFMA(Wh[2][4 + s], H0h, bxn1[s]);
            acc[14 + s] = MFMA(Wh[3][4 + s], H1h, bhn1[s]);
        }
        // round 1: hi-W x lo-in
        #pragma unroll
        for (int tt = 0; tt < 4; ++tt) {
            acc[tt]     = MFMA(Wh[0][tt], xl,  acc[tt]);
            acc[8 + tt] = MFMA(Wh[2][tt], H0l, acc[8 + tt]);
        }
        #pragma unroll
        for (int s = 0; s < 2; ++s) {
            acc[4 + s]  = MFMA(Wh[0][4 + s], xl,  acc[4 + s]);
            acc[6 + s]  = MFMA(Wh[1][4 + s], H0l, acc[6 + s]);
            acc[12 + s] = MFMA(Wh[2][4 + s], H0l, acc[12 + s]);
            acc[14 + s] = MFMA(Wh[3][4 + s], H1l, acc[14 + s]);
        }
        // round 2: lo-W x hi-in
        #pragma unroll
        for (int tt = 0; tt < 4; ++tt) {
            acc[tt]     = MFMA(Wl[0][tt], xh,  acc[tt]);
            acc[8 + tt] = MFMA(Wl[2][tt], H0h, acc[8 + tt]);
        }
        #pragma unroll
        for (int s = 0; s < 2; ++s) {
            acc[4 + s]  = MFMA(Wl[0][4 + s], xh,  acc[4 + s]);
            acc[6 + s]  = MFMA(Wl[1][4 + s], H0h, acc[6 + s]);
            acc[12 + s] = MFMA(Wl[2][4 + s], H0h, acc[12 + s]);
            acc[14 + s] = MFMA(Wl[3][4 + s], H1h, acc[14 + s]);
        }
        // rounds 3-5: rz chains, state-side products (8 chains each round)
        #pragma unroll
        for (int tt = 0; tt < 4; ++tt) {
            acc[tt]     = MFMA(Wh[1][tt], H0h, acc[tt]);
            acc[8 + tt] = MFMA(Wh[3][tt], H1h, acc[8 + tt]);
        }
        #pragma unroll
        for (int tt = 0; tt < 4; ++tt) {
            acc[tt]     = MFMA(Wh[1][tt], H0l, acc[tt]);
            acc[8 + tt] = MFMA(Wh[3][tt], H1l, acc[8 + tt]);
        }
        #pragma unroll
        for (int tt = 0; tt < 4; ++tt) {
            acc[tt]     = MFMA(Wl[1][tt], H0h, acc[tt]);
            acc[8 + tt] = MFMA(Wl[3][tt], H1h, acc[8 + tt]);
        }

        // ---- gates: 16 independent element chains (8 per layer), interleaved ----
        #pragma unroll
        for (int s = 0; s < 2; ++s) {
            #pragma unroll
            for (int j = 0; j < 4; ++j) {
                float r0 = sigmf(acc[s][j]);
                float r1 = sigmf(acc[8 + s][j]);
                float z0 = sigmf(acc[2 + s][j]);
                float z1 = sigmf(acc[10 + s][j]);
                float n0 = tanhf_(fmaf(r0, acc[6 + s][j], acc[4 + s][j]));
                float n1 = tanhf_(fmaf(r1, acc[14 + s][j], acc[12 + s][j]));
                float& h0 = h0f[4 * s + j];
                float& h1 = h1f[4 * s + j];
                h0 = n0 + z0 * (h0 - n0);
                h1 = n1 + z1 * (h1 - n1);
            }
        }
        pack_frag_tr(h0f, H0h, H0l);
        pack_frag_tr(h1f, H1h, H1l);
        xA = nA; xB = nB;
    }

    // ---- epilogue: L1 for final step (input = h0[511], state = h1[510]) ----
    {
        f32x4 a[8];
        #pragma unroll
        for (int tt = 0; tt < 4; ++tt) {
            f32x4 c = MFMA(Wh[2][tt], H0h, brz1[tt]);
            c = MFMA(Wh[2][tt], H0l, c);
            c = MFMA(Wl[2][tt], H0h, c);
            c = MFMA(Wh[3][tt], H1h, c);
            c = MFMA(Wh[3][tt], H1l, c);
            a[tt] = MFMA(Wl[3][tt], H1h, c);
        }
        #pragma unroll
        for (int s = 0; s < 2; ++s) {
            f32x4 c = MFMA(Wh[2][4 + s], H0h, bxn1[s]);
            c = MFMA(Wh[2][4 + s], H0l, c);
            a[4 + s] = MFMA(Wl[2][4 + s], H0h, c);
            f32x4 d = MFMA(Wh[3][4 + s], H1h, bhn1[s]);
            d = MFMA(Wh[3][4 + s], H1l, d);
            a[6 + s] = MFMA(Wl[3][4 + s], H1h, d);
        }
        gate8(a, h1f);
        pack_frag_tr(h1f, H1h, H1l);
    }

    // ---- projection: out[b][o] = b_proj[o] + sum_u W_proj[o][u] * h1[u] ----
    const float* pp = W_proj + r16 * 32 + 4 * q;
    bf16x8 Wph, Wpl;
    split8_tr(*(const f32x4*)pp, *(const f32x4*)(pp + 16), Wph, Wpl);
    f32x4 accp = *(const f32x4*)(b_proj + 4 * q);   // element reg -> output 4q+reg
    accp = MFMA(Wph, H1h, accp);
    accp = MFMA(Wph, H1l, accp);
    accp = MFMA(Wpl, H1h, accp);

    #pragma unroll
    for (int rg = 0; rg < 4; ++rg)
        out[(b0 + r16) * 16 + 4 * q + rg] = accp[rg];
}

extern "C" void kernel_launch(void* const* d_in, const int* in_sizes, int n_in,
                              void* d_out, int out_size, void* d_ws, size_t ws_size,
                              hipStream_t stream) {
    const float* x      = (const float*)d_in[0];
    const float* W_ih0  = (const float*)d_in[1];
    const float* W_hh0  = (const float*)d_in[2];
    const float* b_ih0  = (const float*)d_in[3];
    const float* b_hh0  = (const float*)d_in[4];
    const float* W_ih1  = (const float*)d_in[5];
    const float* W_hh1  = (const float*)d_in[6];
    const float* b_ih1  = (const float*)d_in[7];
    const float* b_hh1  = (const float*)d_in[8];
    const float* W_proj = (const float*)d_in[9];
    const float* b_proj = (const float*)d_in[10];
    float* out = (float*)d_out;

    const int nb   = in_sizes[0] / (T_SEQ * 32);   // 4096 batch elements
    const int grid = nb / 16;                      // 16 batches per 1-wave block

    hipLaunchKernelGGL(gru2_mfma, dim3(grid), dim3(64), 0, stream,
                       x, W_ih0, W_hh0, b_ih0, b_hh0,
                       W_ih1, W_hh1, b_ih1, b_hh1, W_proj, b_proj, out);
}

// Round 5
// 786.574 us; speedup vs baseline: 1.7212x; 1.1085x over previous
//
#include <hip/hip_runtime.h>

using bf16x8 = __attribute__((ext_vector_type(8))) short;
using short8 = __attribute__((ext_vector_type(8))) short;
using f32x4  = __attribute__((ext_vector_type(4))) float;
using u32x4  = __attribute__((ext_vector_type(4))) unsigned;

#define T_SEQ 512
#define MFMA(A, B, C) __builtin_amdgcn_mfma_f32_16x16x32_bf16((A), (B), (C), 0, 0, 0)
#define FENCE() __builtin_amdgcn_sched_barrier(0)

static constexpr float NL2E  = -1.44269504f;   // -log2(e)
static constexpr float N2L2E = -2.88539008f;   // -2*log2(e)

// Truncation split: hi = bf16-truncate(v), lo = bf16-truncate(v - hi) (residual exact).
__device__ __forceinline__ void split8_tr(f32x4 a, f32x4 b, bf16x8& hi, bf16x8& lo) {
    u32x4 ua = __builtin_bit_cast(u32x4, a);
    u32x4 ub = __builtin_bit_cast(u32x4, b);
    u32x4 m  = {0xffff0000u, 0xffff0000u, 0xffff0000u, 0xffff0000u};
    f32x4 ra = a - __builtin_bit_cast(f32x4, ua & m);
    f32x4 rb = b - __builtin_bit_cast(f32x4, ub & m);
    short8 sa  = __builtin_bit_cast(short8, a);
    short8 sb  = __builtin_bit_cast(short8, b);
    short8 sra = __builtin_bit_cast(short8, ra);
    short8 srb = __builtin_bit_cast(short8, rb);
    hi = __builtin_shufflevector(sa, sb, 1, 3, 5, 7, 9, 11, 13, 15);
    lo = __builtin_shufflevector(sra, srb, 1, 3, 5, 7, 9, 11, 13, 15);
}

__device__ __forceinline__ void pack_frag_tr(const float (&hf)[8], bf16x8& hi, bf16x8& lo) {
    f32x4 a = {hf[0], hf[1], hf[2], hf[3]};
    f32x4 b = {hf[4], hf[5], hf[6], hf[7]};
    split8_tr(a, b, hi, lo);
}

// Scalar gates for prologue/epilogue only (rarely executed).
__device__ __forceinline__ float sigmf(float v) {
    return __builtin_amdgcn_rcpf(1.f + __builtin_amdgcn_exp2f(v * NL2E));
}
__device__ __forceinline__ float tanhf_(float v) {
    float e = __builtin_amdgcn_exp2f(fminf(v * N2L2E, 126.f));
    float q = __builtin_amdgcn_rcpf(1.f + e);
    return fmaf(e * q, -2.f, 1.f);
}
__device__ __forceinline__ void gate8(const f32x4 (&a)[8], float (&hf)[8]) {
    #pragma unroll
    for (int s = 0; s < 2; ++s) {
        #pragma unroll
        for (int j = 0; j < 4; ++j) {
            float r = sigmf(a[s][j]);
            float z = sigmf(a[2 + s][j]);
            float nn = tanhf_(fmaf(r, a[6 + s][j], a[4 + s][j]));
            float& h = hf[4 * s + j];
            h = nn + z * (h - nn);
        }
    }
}

// One wave = 16 batches. D = W(96x32)*in(32x16b). Per-lane: batch = b0+(lane&15),
// q = lane>>4; frag elements 0..3 = units 4q+j, 4..7 = units 16+4q+j (same map for
// A and B frags -> correct under any k-slot convention). D: col=lane&15, row=4q+reg.
__global__ __launch_bounds__(64, 1)
void gru2_mfma(const float* __restrict__ x,
               const float* __restrict__ W_ih0, const float* __restrict__ W_hh0,
               const float* __restrict__ b_ih0, const float* __restrict__ b_hh0,
               const float* __restrict__ W_ih1, const float* __restrict__ W_hh1,
               const float* __restrict__ b_ih1, const float* __restrict__ b_hh1,
               const float* __restrict__ W_proj, const float* __restrict__ b_proj,
               float* __restrict__ out)
{
    const int lane = threadIdx.x;
    const int r16  = lane & 15;
    const int q    = lane >> 4;
    const int b0   = blockIdx.x * 16;

    // ---- weight fragments (hi/lo truncation split), register-resident ----
    bf16x8 Wh[4][6], Wl[4][6];
    {
        const float* Ws[4] = {W_ih0, W_hh0, W_ih1, W_hh1};
        #pragma unroll
        for (int m = 0; m < 4; ++m) {
            #pragma unroll
            for (int t = 0; t < 6; ++t) {
                const float* p = Ws[m] + (16 * t + r16) * 32 + 4 * q;
                split8_tr(*(const f32x4*)p, *(const f32x4*)(p + 16), Wh[m][t], Wl[m][t]);
            }
        }
    }

    // ---- bias fragments (acc layout: element reg -> row 16t+4q+reg) ----
    f32x4 brz0[4], brz1[4], bxn0[2], bhn0[2], bxn1[2], bhn1[2];
    #pragma unroll
    for (int t = 0; t < 4; ++t) {
        brz0[t] = *(const f32x4*)(b_ih0 + 16 * t + 4 * q) + *(const f32x4*)(b_hh0 + 16 * t + 4 * q);
        brz1[t] = *(const f32x4*)(b_ih1 + 16 * t + 4 * q) + *(const f32x4*)(b_hh1 + 16 * t + 4 * q);
    }
    #pragma unroll
    for (int t = 0; t < 2; ++t) {
        bxn0[t] = *(const f32x4*)(b_ih0 + 64 + 16 * t + 4 * q);
        bhn0[t] = *(const f32x4*)(b_hh0 + 64 + 16 * t + 4 * q);
        bxn1[t] = *(const f32x4*)(b_ih1 + 64 + 16 * t + 4 * q);
        bhn1[t] = *(const f32x4*)(b_hh1 + 64 + 16 * t + 4 * q);
    }

    // ---- PIN weights+biases in registers: the empty asm is a def the compiler
    // cannot rematerialize a load through, forcing true residency across the loop.
    #pragma unroll
    for (int m = 0; m < 4; ++m)
        #pragma unroll
        for (int t = 0; t < 6; ++t)
            asm volatile("" : "+v"(Wh[m][t]), "+v"(Wl[m][t]));
    #pragma unroll
    for (int t = 0; t < 4; ++t) asm volatile("" : "+v"(brz0[t]), "+v"(brz1[t]));
    #pragma unroll
    for (int t = 0; t < 2; ++t)
        asm volatile("" : "+v"(bxn0[t]), "+v"(bhn0[t]), "+v"(bxn1[t]), "+v"(bhn1[t]));

    // ---- state ----
    bf16x8 H0h = {}, H0l = {}, H1h = {}, H1l = {};
    float h0f[8] = {}, h1f[8] = {};

    const float* xp = x + (size_t)(b0 + r16) * (T_SEQ * 32) + 4 * q;
    f32x4 xA = *(const f32x4*)(xp);
    f32x4 xB = *(const f32x4*)(xp + 16);

    // ---- prologue: L0 step t=0 (h0[-1] = 0) ----
    {
        bf16x8 xh, xl;
        split8_tr(xA, xB, xh, xl);
        xA = *(const f32x4*)(xp + 32);
        xB = *(const f32x4*)(xp + 48);
        f32x4 a[8];
        #pragma unroll
        for (int tt = 0; tt < 4; ++tt) {
            f32x4 c = MFMA(Wh[0][tt], xh, brz0[tt]);
            c = MFMA(Wh[0][tt], xl, c);
            a[tt] = MFMA(Wl[0][tt], xh, c);
        }
        #pragma unroll
        for (int s = 0; s < 2; ++s) {
            f32x4 c = MFMA(Wh[0][4 + s], xh, bxn0[s]);
            c = MFMA(Wh[0][4 + s], xl, c);
            a[4 + s] = MFMA(Wl[0][4 + s], xh, c);
            a[6 + s] = bhn0[s];
        }
        gate8(a, h0f);
        pack_frag_tr(h0f, H0h, H0l);
    }

    // ---- main loop: L1 computes h1[t-1], L0 computes h0[t]; all 72 MFMAs
    // issuable at step start. sched_barrier(0) fences pin the round-robin
    // order (dependent MFMAs >= 8-16 issues apart); gates are level-major so
    // 16 transcendental chains overlap.
    #pragma unroll 1
    for (int t = 1; t < T_SEQ; ++t) {
        bf16x8 xh, xl;
        split8_tr(xA, xB, xh, xl);               // x[t]
        const float* nx = xp + (size_t)((t + 1 < T_SEQ) ? t + 1 : t) * 32;
        f32x4 nA = *(const f32x4*)(nx);          // prefetch x[t+1]
        f32x4 nB = *(const f32x4*)(nx + 16);

        f32x4 acc[16];
        // chains: 0-3 L0 rz | 4-5 L0 xn | 6-7 L0 hn | 8-11 L1 rz | 12-13 L1 xn | 14-15 L1 hn
        // round 0: hi-W x hi-in (C = bias)
        #pragma unroll
        for (int tt = 0; tt < 4; ++tt) {
            acc[tt]     = MFMA(Wh[0][tt], xh,  brz0[tt]);
            acc[8 + tt] = MFMA(Wh[2][tt], H0h, brz1[tt]);
        }
        #pragma unroll
        for (int s = 0; s < 2; ++s) {
            acc[4 + s]  = MFMA(Wh[0][4 + s], xh,  bxn0[s]);
            acc[6 + s]  = MFMA(Wh[1][4 + s], H0h, bhn0[s]);
            acc[12 + s] = MFMA(Wh[2][4 + s], H0h, bxn1[s]);
            acc[14 + s] = MFMA(Wh[3][4 + s], H1h, bhn1[s]);
        }
        FENCE();
        // round 1: hi-W x lo-in
        #pragma unroll
        for (int tt = 0; tt < 4; ++tt) {
            acc[tt]     = MFMA(Wh[0][tt], xl,  acc[tt]);
            acc[8 + tt] = MFMA(Wh[2][tt], H0l, acc[8 + tt]);
        }
        #pragma unroll
        for (int s = 0; s < 2; ++s) {
            acc[4 + s]  = MFMA(Wh[0][4 + s], xl,  acc[4 + s]);
            acc[6 + s]  = MFMA(Wh[1][4 + s], H0l, acc[6 + s]);
            acc[12 + s] = MFMA(Wh[2][4 + s], H0l, acc[12 + s]);
            acc[14 + s] = MFMA(Wh[3][4 + s], H1l, acc[14 + s]);
        }
        FENCE();
        // round 2: lo-W x hi-in
        #pragma unroll
        for (int tt = 0; tt < 4; ++tt) {
            acc[tt]     = MFMA(Wl[0][tt], xh,  acc[tt]);
            acc[8 + tt] = MFMA(Wl[2][tt], H0h, acc[8 + tt]);
        }
        #pragma unroll
        for (int s = 0; s < 2; ++s) {
            acc[4 + s]  = MFMA(Wl[0][4 + s], xh,  acc[4 + s]);
            acc[6 + s]  = MFMA(Wl[1][4 + s], H0h, acc[6 + s]);
            acc[12 + s] = MFMA(Wl[2][4 + s], H0h, acc[12 + s]);
            acc[14 + s] = MFMA(Wl[3][4 + s], H1h, acc[14 + s]);
        }
        FENCE();
        // rounds 3-5: rz chains, state-side products
        #pragma unroll
        for (int tt = 0; tt < 4; ++tt) {
            acc[tt]     = MFMA(Wh[1][tt], H0h, acc[tt]);
            acc[8 + tt] = MFMA(Wh[3][tt], H1h, acc[8 + tt]);
        }
        FENCE();
        #pragma unroll
        for (int tt = 0; tt < 4; ++tt) {
            acc[tt]     = MFMA(Wh[1][tt], H0l, acc[tt]);
            acc[8 + tt] = MFMA(Wh[3][tt], H1l, acc[8 + tt]);
        }
        FENCE();
        #pragma unroll
        for (int tt = 0; tt < 4; ++tt) {
            acc[tt]     = MFMA(Wl[1][tt], H0h, acc[tt]);
            acc[8 + tt] = MFMA(Wl[3][tt], H1h, acc[8 + tt]);
        }
        FENCE();

        // ---- gates, level-major over 16 independent element chains ----
        // e 0..7 -> L0 unit (e&7); e 8..15 -> L1. acc index renames (no ops).
        float vr[16], vz[16], vax[16], vah[16], hOld[16];
        #pragma unroll
        for (int e = 0; e < 16; ++e) {
            const int L = e >> 3, s = (e >> 2) & 1, j = e & 3;
            vr[e]  = acc[8 * L + s][j];
            vz[e]  = acc[8 * L + 2 + s][j];
            vax[e] = acc[8 * L + 4 + s][j];
            vah[e] = acc[8 * L + 6 + s][j];
            hOld[e] = L ? h1f[e & 7] : h0f[e & 7];
        }
        float er[16], ez[16];
        #pragma unroll
        for (int e = 0; e < 16; ++e) er[e] = __builtin_amdgcn_exp2f(vr[e] * NL2E);
        #pragma unroll
        for (int e = 0; e < 16; ++e) ez[e] = __builtin_amdgcn_exp2f(vz[e] * NL2E);
        FENCE();
        float gr[16], gz[16];
        #pragma unroll
        for (int e = 0; e < 16; ++e) gr[e] = __builtin_amdgcn_rcpf(1.f + er[e]);
        #pragma unroll
        for (int e = 0; e < 16; ++e) gz[e] = __builtin_amdgcn_rcpf(1.f + ez[e]);
        FENCE();
        float en[16];
        #pragma unroll
        for (int e = 0; e < 16; ++e) {
            float u = fmaf(gr[e], vah[e], vax[e]);
            en[e] = __builtin_amdgcn_exp2f(fminf(u * N2L2E, 126.f));
        }
        FENCE();
        float qn[16];
        #pragma unroll
        for (int e = 0; e < 16; ++e) qn[e] = __builtin_amdgcn_rcpf(1.f + en[e]);
        FENCE();
        #pragma unroll
        for (int e = 0; e < 16; ++e) {
            float nn = fmaf(en[e] * qn[e], -2.f, 1.f);
            hOld[e] = fmaf(gz[e], hOld[e] - nn, nn);
        }
        #pragma unroll
        for (int e = 0; e < 8; ++e) { h0f[e] = hOld[e]; h1f[e] = hOld[8 + e]; }
        FENCE();
        pack_frag_tr(h0f, H0h, H0l);
        pack_frag_tr(h1f, H1h, H1l);
        xA = nA; xB = nB;
    }

    // ---- epilogue: L1 for final step (input = h0[511], state = h1[510]) ----
    {
        f32x4 a[8];
        #pragma unroll
        for (int tt = 0; tt < 4; ++tt) {
            f32x4 c = MFMA(Wh[2][tt], H0h, brz1[tt]);
            c = MFMA(Wh[2][tt], H0l, c);
            c = MFMA(Wl[2][tt], H0h, c);
            c = MFMA(Wh[3][tt], H1h, c);
            c = MFMA(Wh[3][tt], H1l, c);
            a[tt] = MFMA(Wl[3][tt], H1h, c);
        }
        #pragma unroll
        for (int s = 0; s < 2; ++s) {
            f32x4 c = MFMA(Wh[2][4 + s], H0h, bxn1[s]);
            c = MFMA(Wh[2][4 + s], H0l, c);
            a[4 + s] = MFMA(Wl[2][4 + s], H0h, c);
            f32x4 d = MFMA(Wh[3][4 + s], H1h, bhn1[s]);
            d = MFMA(Wh[3][4 + s], H1l, d);
            a[6 + s] = MFMA(Wl[3][4 + s], H1h, d);
        }
        gate8(a, h1f);
        pack_frag_tr(h1f, H1h, H1l);
    }

    // ---- projection: out[b][o] = b_proj[o] + sum_u W_proj[o][u] * h1[u] ----
    const float* pp = W_proj + r16 * 32 + 4 * q;
    bf16x8 Wph, Wpl;
    split8_tr(*(const f32x4*)pp, *(const f32x4*)(pp + 16), Wph, Wpl);
    f32x4 accp = *(const f32x4*)(b_proj + 4 * q);   // element reg -> output 4q+reg
    accp = MFMA(Wph, H1h, accp);
    accp = MFMA(Wph, H1l, accp);
    accp = MFMA(Wpl, H1h, accp);

    #pragma unroll
    for (int rg = 0; rg < 4; ++rg)
        out[(b0 + r16) * 16 + 4 * q + rg] = accp[rg];
}

extern "C" void kernel_launch(void* const* d_in, const int* in_sizes, int n_in,
                              void* d_out, int out_size, void* d_ws, size_t ws_size,
                              hipStream_t stream) {
    const float* x      = (const float*)d_in[0];
    const float* W_ih0  = (const float*)d_in[1];
    const float* W_hh0  = (const float*)d_in[2];
    const float* b_ih0  = (const float*)d_in[3];
    const float* b_hh0  = (const float*)d_in[4];
    const float* W_ih1  = (const float*)d_in[5];
    const float* W_hh1  = (const float*)d_in[6];
    const float* b_ih1  = (const float*)d_in[7];
    const float* b_hh1  = (const float*)d_in[8];
    const float* W_proj = (const float*)d_in[9];
    const float* b_proj = (const float*)d_in[10];
    float* out = (float*)d_out;

    const int nb   = in_sizes[0] / (T_SEQ * 32);   // 4096 batch elements
    const int grid = nb / 16;                      // 16 batches per 1-wave block

    hipLaunchKernelGGL(gru2_mfma, dim3(grid), dim3(64), 0, stream,
                       x, W_ih0, W_hh0, b_ih0, b_hh0,
                       W_ih1, W_hh1, b_ih1, b_hh1, W_proj, b_proj, out);
}